// Round 1
// baseline (156.170 us; speedup 1.0000x reference)
//
#include <hip/hip_runtime.h>

// Trig tables in d_ws as float2 = (cos, sin):
// [0..15]     conv1_weight (4*1*2*2 = 16):  idx = o*4 + dy*2 + dx
// [16..527]   conv2_weight (8*4*4*4 = 512): idx = o*64 + c*16 + dy*4 + dx
// [528..3407] ff_weight    (288*10 = 2880): idx = f*10 + n
#define WT_W1 0
#define WT_W2 16
#define WT_FF 528

__global__ void ringnn_setup(const float* __restrict__ w1,
                             const float* __restrict__ w2,
                             const float* __restrict__ ffw,
                             float2* __restrict__ wt) {
    int t = blockIdx.x * blockDim.x + threadIdx.x;
    float s, c;
    if (t < 16)   { __sincosf(w1[t],  &s, &c); wt[WT_W1 + t] = make_float2(c, s); }
    if (t < 512)  { __sincosf(w2[t],  &s, &c); wt[WT_W2 + t] = make_float2(c, s); }
    if (t < 2880) { __sincosf(ffw[t], &s, &c); wt[WT_FF + t] = make_float2(c, s); }
}

// One block (1 wave, 64 threads) per batch image.
__global__ __launch_bounds__(64) void ringnn_main(
    const float* __restrict__ x,
    const float2* __restrict__ wt,
    float* __restrict__ out)
{
    // bufA: phase0 holds (cos,sin) of the 28x28 input; after stage 1 it is
    // reused: [0..287] = stage-2 output unit vectors, [512..575] = stage-3
    // reduction scratch.
    __shared__ float2 bufA[784];
    __shared__ float2 cs1[784];   // stage-1 output, layout [c][14][14] = c*196 + i*14 + j

    const int t = threadIdx.x;
    const int b = blockIdx.x;
    const float* xb = x + b * 784;

    // ---- Phase 0: unit vectors of the input pixels ----
    for (int p = t; p < 784; p += 64) {
        float s, c;
        __sincosf(xb[p], &s, &c);
        bufA[p] = make_float2(c, s);
    }
    __syncthreads();

    // ---- Stage 1: ring-conv 2x2 stride 2, 1->4 ch, 28x28 -> 14x14 ----
    // output idx = o*196 + i*14 + j  (matches cs1 layout directly)
    for (int idx = t; idx < 784; idx += 64) {
        const int o   = idx / 196;
        const int pos = idx - o * 196;
        const int i   = pos / 14;
        const int j   = pos - i * 14;
        const float2* xw = bufA + (2 * i) * 28 + 2 * j;
        const float2* ww = wt + WT_W1 + o * 4;
        float X = 0.f, Y = 0.f;
        #pragma unroll
        for (int dy = 0; dy < 2; ++dy) {
            #pragma unroll
            for (int dx = 0; dx < 2; ++dx) {
                float2 v = xw[dy * 28 + dx];
                float2 w = ww[dy * 2 + dx];
                // Z += v * conj(w):  X += vc*wc + vs*ws ; Y += vs*wc - vc*ws
                X = fmaf(v.x, w.x, X); X = fmaf(v.y, w.y, X);
                Y = fmaf(v.y, w.x, Y); Y = fmaf(-v.x, w.y, Y);
            }
        }
        float rinv = rsqrtf(fmaxf(fmaf(X, X, Y * Y), 1e-30f));
        cs1[idx] = make_float2(X * rinv, Y * rinv);
    }
    __syncthreads();

    // ---- Stage 2: ring-conv 4x4 stride 2, 4->8 ch, 14x14 -> 6x6 ----
    // output f = (i*6 + j)*8 + o   (matches the reference reshape order)
    float2* cs2 = bufA;  // [0..287]
    for (int idx = t; idx < 288; idx += 64) {
        const int o   = idx & 7;
        const int pos = idx >> 3;
        const int i   = pos / 6;
        const int j   = pos - i * 6;
        const float2* wb = wt + WT_W2 + o * 64;
        float X = 0.f, Y = 0.f;
        #pragma unroll
        for (int c = 0; c < 4; ++c) {
            const float2* ib = cs1 + c * 196 + (2 * i) * 14 + 2 * j;
            const float2* wc = wb + c * 16;
            #pragma unroll
            for (int dy = 0; dy < 4; ++dy) {
                #pragma unroll
                for (int dx = 0; dx < 4; ++dx) {
                    float2 v = ib[dy * 14 + dx];
                    float2 w = wc[dy * 4 + dx];
                    X = fmaf(v.x, w.x, X); X = fmaf(v.y, w.y, X);
                    Y = fmaf(v.y, w.x, Y); Y = fmaf(-v.x, w.y, Y);
                }
            }
        }
        float rinv = rsqrtf(fmaxf(fmaf(X, X, Y * Y), 1e-30f));
        cs2[idx] = make_float2(X * rinv, Y * rinv);
    }
    __syncthreads();

    // ---- Stage 3: ring-FF 288 -> 10, out = sin(angle) = Y/r ----
    // lane = n*6 + g : lane handles output n, feature chunk f in [g*48, g*48+48)
    float2* red = bufA + 512;     // [512..575], does not overlap cs2[0..287]
    {
        float X = 0.f, Y = 0.f;
        const int n = t / 6;
        const int g = t - n * 6;
        if (n < 10) {
            const float2* wn = wt + WT_FF + n;
            const float2* c2 = cs2 + g * 48;
            #pragma unroll 8
            for (int k = 0; k < 48; ++k) {
                float2 v = c2[k];
                float2 w = wn[(g * 48 + k) * 10];
                X = fmaf(v.x, w.x, X); X = fmaf(v.y, w.y, X);
                Y = fmaf(v.y, w.x, Y); Y = fmaf(-v.x, w.y, Y);
            }
        }
        red[t] = make_float2(X, Y);
    }
    __syncthreads();
    if (t < 10) {
        float Xs = 0.f, Ys = 0.f;
        #pragma unroll
        for (int g2 = 0; g2 < 6; ++g2) {
            float2 p = red[t * 6 + g2];
            Xs += p.x; Ys += p.y;
        }
        float rinv = rsqrtf(fmaxf(fmaf(Xs, Xs, Ys * Ys), 1e-30f));
        out[b * 10 + t] = Ys * rinv;
    }
}

extern "C" void kernel_launch(void* const* d_in, const int* in_sizes, int n_in,
                              void* d_out, int out_size, void* d_ws, size_t ws_size,
                              hipStream_t stream) {
    const float* x   = (const float*)d_in[0];
    const float* w1  = (const float*)d_in[1];
    const float* w2  = (const float*)d_in[2];
    const float* ffw = (const float*)d_in[3];
    float2* wt = (float2*)d_ws;            // needs 3408*8 = 27264 bytes
    float* o   = (float*)d_out;

    ringnn_setup<<<12, 256, 0, stream>>>(w1, w2, ffw, wt);
    ringnn_main<<<4096, 64, 0, stream>>>(x, wt, o);
}

// Round 2
// 110.764 us; speedup vs baseline: 1.4099x; 1.4099x over previous
//
#include <hip/hip_runtime.h>

// d_ws layout: 3408 x uint2 (half4 each): lo = half2(cos,sin) [for X-dot],
//                                         hi = half2(cos,-sin) [for Y-dot]
// [0..15]     conv1 (o*4 + dy*2 + dx)
// [16..527]   conv2 (o*64 + c*16 + dy*4 + dx)
// [528..3407] ff    (f*10 + n)
#define WT_W1 0
#define WT_W2 16
#define WT_FF 528

typedef _Float16 h2 __attribute__((ext_vector_type(2)));

__device__ __forceinline__ float fdot2(unsigned a, unsigned b, float c) {
    return __builtin_amdgcn_fdot2(__builtin_bit_cast(h2, a),
                                  __builtin_bit_cast(h2, b), c, false);
}
__device__ __forceinline__ unsigned swap16(unsigned v) {
    return (v >> 16) | (v << 16);   // v_alignbit_b32
}
__device__ __forceinline__ unsigned packh2(float x, float y) {
    h2 h; h.x = (_Float16)x; h.y = (_Float16)y;
    return __builtin_bit_cast(unsigned, h);
}

__global__ void ringnn_setup(const float* __restrict__ w1,
                             const float* __restrict__ w2,
                             const float* __restrict__ ffw,
                             uint2* __restrict__ wt) {
    int t = blockIdx.x * blockDim.x + threadIdx.x;
    if (t >= 3408) return;
    float a;
    if (t < 16)        a = w1[t];
    else if (t < 528)  a = w2[t - 16];
    else               a = ffw[t - 528];
    float s, c;
    __sincosf(a, &s, &c);
    uint2 v;
    v.x = packh2(c, s);
    v.y = packh2(c, -s);
    wt[t] = v;
}

// 256 threads = 4 waves; wave w handles image blockIdx.x*4 + w.
__global__ __launch_bounds__(256) void ringnn_main(
    const float* __restrict__ x,
    const uint2* __restrict__ wt,
    float* __restrict__ out)
{
    __shared__ uint2 w1t[16];
    __shared__ uint4 w2t[256];              // 512 taps as (wX,wY) uint2 pairs
    __shared__ unsigned cs1[4][784];        // [img][c*196 + i*14 + j], half2
    __shared__ unsigned cs2[4][288];        // [img][(i*6+j)*8 + o], half2

    const int t    = threadIdx.x;
    const int wv   = t >> 6;
    const int lane = t & 63;
    const int b    = blockIdx.x * 4 + wv;
    const float* xb = x + b * 784;

    // ---- Load weight tables into LDS (block-cooperative) ----
    for (int k = t; k < 528; k += 256) {
        uint2 val = wt[k];
        if (k < 16) w1t[k] = val;
        else        ((uint2*)w2t)[k - 16] = val;
    }
    __syncthreads();

    // ---- Stage 1: sincos from global + 2x2/s2 conv, 1->4 ch ----
    for (int pos = lane; pos < 196; pos += 64) {
        const int i = pos / 14;
        const int j = pos - i * 14;
        const float* px = xb + (2 * i) * 28 + 2 * j;
        float2 p0 = *(const float2*)(px);
        float2 p1 = *(const float2*)(px + 28);
        float s0, c0, s1, c1, s2, c2, s3, c3;
        __sincosf(p0.x, &s0, &c0);
        __sincosf(p0.y, &s1, &c1);
        __sincosf(p1.x, &s2, &c2);
        __sincosf(p1.y, &s3, &c3);
        unsigned v0 = packh2(c0, s0), v1 = packh2(c1, s1);
        unsigned v2 = packh2(c2, s2), v3 = packh2(c3, s3);
        unsigned sv0 = swap16(v0), sv1 = swap16(v1);
        unsigned sv2 = swap16(v2), sv3 = swap16(v3);
        #pragma unroll
        for (int o = 0; o < 4; ++o) {
            uint2 wa = w1t[o * 4 + 0], wb = w1t[o * 4 + 1];
            uint2 wc = w1t[o * 4 + 2], wd = w1t[o * 4 + 3];
            float X = 0.f, Y = 0.f;
            X = fdot2(v0, wa.x, X); Y = fdot2(sv0, wa.y, Y);
            X = fdot2(v1, wb.x, X); Y = fdot2(sv1, wb.y, Y);
            X = fdot2(v2, wc.x, X); Y = fdot2(sv2, wc.y, Y);
            X = fdot2(v3, wd.x, X); Y = fdot2(sv3, wd.y, Y);
            float rinv = rsqrtf(fmaxf(fmaf(X, X, Y * Y), 1e-30f));
            cs1[wv][o * 196 + pos] = packh2(X * rinv, Y * rinv);
        }
    }
    __syncthreads();

    // ---- Stage 2: 4x4/s2 conv, 4->8 ch, 14x14 -> 6x6 ----
    for (int idx = lane; idx < 288; idx += 64) {
        const int o   = idx & 7;
        const int pos = idx >> 3;
        const int i   = pos / 6;
        const int j   = pos - i * 6;
        const unsigned* cbase = &cs1[wv][(2 * i) * 14 + 2 * j];
        const uint4*    wbase = &w2t[o * 32];
        float X = 0.f, Y = 0.f;
        #pragma unroll
        for (int c = 0; c < 4; ++c) {
            #pragma unroll
            for (int dy = 0; dy < 4; ++dy) {
                const unsigned* r = cbase + c * 196 + dy * 14;  // 8B aligned
                uint2 va = *(const uint2*)(r);
                uint2 vb = *(const uint2*)(r + 2);
                uint4 wA = wbase[c * 8 + dy * 2 + 0];  // taps dx=0,1
                uint4 wB = wbase[c * 8 + dy * 2 + 1];  // taps dx=2,3
                X = fdot2(va.x, wA.x, X); Y = fdot2(swap16(va.x), wA.y, Y);
                X = fdot2(va.y, wA.z, X); Y = fdot2(swap16(va.y), wA.w, Y);
                X = fdot2(vb.x, wB.x, X); Y = fdot2(swap16(vb.x), wB.y, Y);
                X = fdot2(vb.y, wB.z, X); Y = fdot2(swap16(vb.y), wB.w, Y);
            }
        }
        float rinv = rsqrtf(fmaxf(fmaf(X, X, Y * Y), 1e-30f));
        cs2[wv][idx] = packh2(X * rinv, Y * rinv);
    }
    __syncthreads();

    // ---- Stage 3: ring-FF 288 -> 10, out = sin(angle) = Y/r ----
    // lane = n*6 + g: output n, feature chunk [g*48, g*48+48)
    float2* red = (float2*)cs1[wv];   // cs1 free now; 64 float2 scratch
    {
        float X = 0.f, Y = 0.f;
        const int n = lane / 6;
        const int g = lane - n * 6;
        if (n < 10) {
            const uint2* wn = wt + WT_FF + n;
            const unsigned* c2 = &cs2[wv][g * 48];
            #pragma unroll 4
            for (int k = 0; k < 48; ++k) {
                unsigned v = c2[k];
                uint2 wvv = wn[(g * 48 + k) * 10];
                X = fdot2(v, wvv.x, X);
                Y = fdot2(swap16(v), wvv.y, Y);
            }
        }
        red[lane] = make_float2(X, Y);
    }
    __syncthreads();
    if (lane < 10) {
        float Xs = 0.f, Ys = 0.f;
        #pragma unroll
        for (int g2 = 0; g2 < 6; ++g2) {
            float2 p = red[lane * 6 + g2];
            Xs += p.x; Ys += p.y;
        }
        float rinv = rsqrtf(fmaxf(fmaf(Xs, Xs, Ys * Ys), 1e-30f));
        out[b * 10 + lane] = Ys * rinv;
    }
}

extern "C" void kernel_launch(void* const* d_in, const int* in_sizes, int n_in,
                              void* d_out, int out_size, void* d_ws, size_t ws_size,
                              hipStream_t stream) {
    const float* x   = (const float*)d_in[0];
    const float* w1  = (const float*)d_in[1];
    const float* w2  = (const float*)d_in[2];
    const float* ffw = (const float*)d_in[3];
    uint2* wt = (uint2*)d_ws;              // needs 3408*8 = 27264 bytes
    float* o  = (float*)d_out;

    ringnn_setup<<<14, 256, 0, stream>>>(w1, w2, ffw, wt);
    ringnn_main<<<1024, 256, 0, stream>>>(x, wt, o);
}